// Round 4
// baseline (331.787 us; speedup 1.0000x reference)
//
#include <hip/hip_runtime.h>

// Problem constants
#define DIMD 768
#define NTOK 2048
#define NB   8

typedef __attribute__((ext_vector_type(8))) short bfrag8;
typedef __attribute__((ext_vector_type(4))) float accf4;

// float -> bf16 bits, round-to-nearest-even (finite inputs)
__device__ __forceinline__ unsigned short f2bf(float f) {
  unsigned u = __float_as_uint(f);
  return (unsigned short)((u + 0x7fffu + ((u >> 16) & 1u)) >> 16);
}

// async 16B global -> LDS (wave-uniform base + lane*16 semantics)
__device__ __forceinline__ void glds16(const void* g, void* l) {
  __builtin_amdgcn_global_load_lds(
      (const __attribute__((address_space(1))) void*)g,
      (__attribute__((address_space(3))) void*)l, 16, 0, 0);
}

// ---------------------------------------------------------------------------
// device bodies
// ---------------------------------------------------------------------------

// pack W1|W2 -> Wcat bf16 [768][1536]
__device__ __forceinline__ void packw_body(int blk, const float* __restrict__ W1,
                                           const float* __restrict__ W2,
                                           unsigned short* __restrict__ Wcat) {
  int gid = blk * 256 + threadIdx.x;           // one per 4 elems
  int r = gid / 192, c4 = (gid % 192) * 4;
  float4 a = *(const float4*)(W1 + (size_t)r * DIMD + c4);
  float4 b = *(const float4*)(W2 + (size_t)r * DIMD + c4);
  union { unsigned short us[4]; uint2 u2; } ra, rb;
  ra.us[0] = f2bf(a.x); ra.us[1] = f2bf(a.y); ra.us[2] = f2bf(a.z); ra.us[3] = f2bf(a.w);
  rb.us[0] = f2bf(b.x); rb.us[1] = f2bf(b.y); rb.us[2] = f2bf(b.z); rb.us[3] = f2bf(b.w);
  *(uint2*)(Wcat + (size_t)r * 1536 + c4) = ra.u2;
  *(uint2*)(Wcat + (size_t)r * 1536 + 768 + c4) = rb.u2;
}

// pack x -> bf16 (one thread per 8 floats)
__device__ __forceinline__ void packx_body(int blk, const float* __restrict__ x,
                                           unsigned short* __restrict__ xb) {
  size_t gid = (size_t)blk * 256 + threadIdx.x;
  const float4* x4 = (const float4*)x;
  float4 v0 = x4[gid * 2], v1 = x4[gid * 2 + 1];
  union { unsigned short us[8]; uint4 u4; } r;
  r.us[0] = f2bf(v0.x); r.us[1] = f2bf(v0.y); r.us[2] = f2bf(v0.z); r.us[3] = f2bf(v0.w);
  r.us[4] = f2bf(v1.x); r.us[5] = f2bf(v1.y); r.us[6] = f2bf(v1.z); r.us[7] = f2bf(v1.w);
  ((uint4*)xb)[gid] = r.u4;
}

// BT-format bf16 MFMA GEMM body: C[m][n] = sum_k A[m][k] * B[n][k]
// Tile (64*TMD) x (64*TND), 4 waves, BK=64, glds16 staging.
// Double-buffered LDS, prefetch-before-compute, one fused
// "s_waitcnt vmcnt(0); s_barrier" per K-step.
// LDS bank-conflict swizzle (both-sides-or-neither): LDS dest stays linear
// (glds16 requirement); the 16B slot within each row is permuted on the
// GLOBAL source side (scol) and identically on the fragment-read side.
// bid & 7 -> batch (XCD affinity).
// EPI 0: store bf16.
// EPI 1: f32 epilogue gate*acc + gate*(b1+b2) + x.
// EPI 2: bf16 store scaled by per-column inv-colsum (b1v = csp partials [b][32][768]).
template <int TMD, int TND, int EPI>
__device__ __forceinline__ void gemm_body(
    unsigned short* As, unsigned short* Bs, int bid,
    const unsigned short* __restrict__ A, const unsigned short* __restrict__ B,
    void* __restrict__ Cout, int K, int lda, int ldb, int ldc, int ntx,
    long long sA, long long sB, long long sC,
    const float* __restrict__ wg, const float* __restrict__ b1v,
    const float* __restrict__ b2v, const float* __restrict__ xres) {
  constexpr int TM = 64 * TMD, TN = 64 * TND;
  constexpr int ASZ = TM * 64, BSZ = TN * 64;  // shorts per LDS buffer
  __shared__ float csi[64 * TND];              // EPI==2: inv colsum per C column
  const int t = threadIdx.x, w = t >> 6, lane = t & 63;
  const int bz = bid & 7;
  const int r = bid >> 3;
  const int by = r / ntx, bx = r - by * ntx;
  const int m0 = by * TM, n0 = bx * TN;
  const unsigned short* Ab = A + (size_t)bz * sA;
  const unsigned short* Bb = B + (size_t)bz * sB;
  const int srow = lane >> 3;          // 0..7 (row within 8-row chunk)
  // swizzled 16B slot: slot' = slot ^ (row&7)
  const int scol = (((lane & 7) ^ (lane >> 3)) * 8);

  auto stage = [&](int buf, int k0) {
    unsigned short* Ad = As + buf * ASZ;
    unsigned short* Bd = Bs + buf * BSZ;
#pragma unroll
    for (int l = 0; l < 2 * TND; ++l) {
      int chunk = l * 4 + w;
      int row = chunk * 8 + srow;
      glds16(Bb + (size_t)(n0 + row) * ldb + k0 + scol,
             (char*)Bd + chunk * 1024 + lane * 16);
    }
#pragma unroll
    for (int l = 0; l < 2 * TMD; ++l) {
      int chunk = l * 4 + w;
      int row = chunk * 8 + srow;
      glds16(Ab + (size_t)(m0 + row) * lda + k0 + scol,
             (char*)Ad + chunk * 1024 + lane * 16);
    }
  };

  stage(0, 0);

  if (EPI == 2) {
    // merge 32 colsum partials -> 1/sum for this block's output columns
    for (int c = t; c < TN; c += 256) {
      const float* cp = b1v + (size_t)bz * 32 * DIMD + n0 + c;
      float s = 0.f;
#pragma unroll
      for (int p = 0; p < 32; ++p) s += cp[(size_t)p * DIMD];
      csi[c] = 1.0f / s;
    }
  }

  accf4 zero = {0.f, 0.f, 0.f, 0.f};
  accf4 acc[2 * TMD][2 * TND];
#pragma unroll
  for (int i = 0; i < 2 * TMD; ++i)
#pragma unroll
    for (int j = 0; j < 2 * TND; ++j) acc[i][j] = zero;

  const int wm = (w & 1) * (32 * TMD), wn = (w >> 1) * (32 * TND);
  const int lm = lane & 15, qd = lane >> 4;
  const int lsw = (lm & 7) << 3;       // read-side swizzle XOR (in shorts)

  // drains stage(0) (syncthreads implies vmcnt(0)+lgkmcnt(0)) and makes csi visible
  __syncthreads();

  const int nt = K / 64;
  int cur = 0;
#pragma unroll 2
  for (int tt = 0; tt < nt; ++tt) {
    if (tt + 1 < nt) stage(cur ^ 1, (tt + 1) * 64);
    const unsigned short* Ar = As + cur * ASZ;
    const unsigned short* Br = Bs + cur * BSZ;
#pragma unroll
    for (int kc = 0; kc < 2; ++kc) {
      bfrag8 av[2 * TMD], bv[2 * TND];
      const int kslot = (((kc << 2) | qd) << 3) ^ lsw;   // swizzled 16B slot
#pragma unroll
      for (int i = 0; i < 2 * TMD; ++i)
        av[i] = *(const bfrag8*)(Ar + (wm + i * 16 + lm) * 64 + kslot);
#pragma unroll
      for (int j = 0; j < 2 * TND; ++j)
        bv[j] = *(const bfrag8*)(Br + (wn + j * 16 + lm) * 64 + kslot);
      __builtin_amdgcn_s_setprio(1);
#pragma unroll
      for (int i = 0; i < 2 * TMD; ++i)
#pragma unroll
        for (int j = 0; j < 2 * TND; ++j)
          acc[i][j] = __builtin_amdgcn_mfma_f32_16x16x32_bf16(av[i], bv[j], acc[i][j], 0, 0, 0);
      __builtin_amdgcn_s_setprio(0);
    }
    if (tt + 1 < nt) {
      // fused: wait own stage loads, then workgroup barrier. All ds_reads of
      // buf[cur] were consumed by MFMAs above, so buf[cur] is free to restage.
      asm volatile("s_waitcnt vmcnt(0)\n\ts_barrier" ::: "memory");
    }
    cur ^= 1;
  }

  if (EPI == 0) {
    unsigned short* Cb = (unsigned short*)Cout + (size_t)bz * sC;
#pragma unroll
    for (int i = 0; i < 2 * TMD; ++i)
#pragma unroll
      for (int j = 0; j < 2 * TND; ++j) {
        int col = n0 + wn + j * 16 + lm;
#pragma unroll
        for (int rr = 0; rr < 4; ++rr) {
          int row = m0 + wm + i * 16 + qd * 4 + rr;
          Cb[(size_t)row * ldc + col] = f2bf(acc[i][j][rr]);
        }
      }
  } else if (EPI == 1) {
    float gate = 1.f / (1.f + __expf(-wg[0]));
    float* Co = (float*)Cout + (size_t)bz * sC;
    const float* Xr = xres + (size_t)bz * sC;
#pragma unroll
    for (int j = 0; j < 2 * TND; ++j) {
      int col = n0 + wn + j * 16 + lm;
      float gb = gate * (b1v[col] + b2v[col]);
#pragma unroll
      for (int i = 0; i < 2 * TMD; ++i)
#pragma unroll
        for (int rr = 0; rr < 4; ++rr) {
          int row = m0 + wm + i * 16 + qd * 4 + rr;
          size_t idx = (size_t)row * ldc + col;
          Co[idx] = gate * acc[i][j][rr] + gb + Xr[idx];
        }
    }
  } else {
    unsigned short* Cb = (unsigned short*)Cout + (size_t)bz * sC;
#pragma unroll
    for (int j = 0; j < 2 * TND; ++j) {
      int lc = wn + j * 16 + lm;
      int col = n0 + lc;
      float ci = csi[lc];
#pragma unroll
      for (int i = 0; i < 2 * TMD; ++i)
#pragma unroll
        for (int rr = 0; rr < 4; ++rr) {
          int row = m0 + wm + i * 16 + qd * 4 + rr;
          Cb[(size_t)row * ldc + col] = f2bf(acc[i][j][rr] * ci);
        }
    }
  }
}

// ---------------------------------------------------------------------------
// stage1: fused rowsum + exp + transpose (+ packw), 32 tokens/block.
// 32-token tile keeps LDS at 61.4 KB -> 2 blocks/CU (the 64-token version's
// 108 KB etile forced 1 block/CU = 1 wave/SIMD and was latency-bound at
// 2.3 TB/s). Reads x once, computes exp once, rowsum in-block (8-lane
// shuffle); Kt = exp*rowsum_inv, Qt = raw exp bits. Column-sum partials keep
// the [b][32][768] 64-token-tile layout: the two 32-token blocks of a tile
// combine via atomicAdd (exactly 2 commutative adds -> deterministic);
// csp is zeroed by a hipMemsetAsync before launch.
// blocks [0,nsm): softmax (sel = blk>>9 picks A/B set, 512 blocks each)
// blocks [nsm, nsm+npw): packw
// ---------------------------------------------------------------------------
__global__ __launch_bounds__(256) void stage1_kernel(
    const float* __restrict__ xA, unsigned short* __restrict__ KtA,
    unsigned short* __restrict__ QtA, float* __restrict__ cspA,
    const float* __restrict__ xB, unsigned short* __restrict__ KtB,
    unsigned short* __restrict__ QtB, float* __restrict__ cspB,
    int nsm,
    const float* __restrict__ W1, const float* __restrict__ W2,
    unsigned short* __restrict__ Wcat, int npw) {
  int blk = blockIdx.x;
  if (blk >= nsm) {
    if (blk < nsm + npw) packw_body(blk - nsm, W1, W2, Wcat);
    return;
  }
  __shared__ float rowsi[32];
  __shared__ __align__(16) unsigned short etile[768 * 40];  // stride 80B (16B-aligned rows)
  const int sel = blk >> 9;
  const float* xin = sel ? xB : xA;
  unsigned short* Kt = sel ? KtB : KtA;
  unsigned short* Qt = sel ? QtB : QtA;
  float* csp = sel ? cspB : cspA;
  const int lb = blk & 511;
  const int b = lb >> 6, tile = lb & 63, n0 = tile * 32;
  const int t = threadIdx.x;

  // phase A: exp + transposed LDS store + rowsum (8 threads/token, 96 dims each)
  const int tok = t >> 3, seg = t & 7;
  const float* row = xin + ((size_t)b * NTOK + n0 + tok) * DIMD + seg * 96;
  float s = 0.f;
#pragma unroll 8
  for (int j = 0; j < 24; ++j) {
    float4 v = *(const float4*)(row + j * 4);
    float e0 = __expf(v.x), e1 = __expf(v.y), e2 = __expf(v.z), e3 = __expf(v.w);
    s += (e0 + e1) + (e2 + e3);
    int d = seg * 96 + j * 4;
    etile[(d + 0) * 40 + tok] = f2bf(e0);
    etile[(d + 1) * 40 + tok] = f2bf(e1);
    etile[(d + 2) * 40 + tok] = f2bf(e2);
    etile[(d + 3) * 40 + tok] = f2bf(e3);
  }
  s += __shfl_xor(s, 1, 64);
  s += __shfl_xor(s, 2, 64);
  s += __shfl_xor(s, 4, 64);
  if (seg == 0) rowsi[tok] = 1.0f / s;
  __syncthreads();

  // phase B: read back 8-token groups, write Kt (scaled) + Qt (raw) + csp
#pragma unroll 4
  for (int q = 0; q < 12; ++q) {
    int dl = (t >> 2) + q * 64;                  // 0..767
    int g = t & 3;                               // 4 groups of 8 tokens
    uint4 e8 = *(const uint4*)(etile + dl * 40 + g * 8);
    float ef[8];
    ef[0] = __uint_as_float(e8.x << 16); ef[1] = __uint_as_float(e8.x & 0xffff0000u);
    ef[2] = __uint_as_float(e8.y << 16); ef[3] = __uint_as_float(e8.y & 0xffff0000u);
    ef[4] = __uint_as_float(e8.z << 16); ef[5] = __uint_as_float(e8.z & 0xffff0000u);
    ef[6] = __uint_as_float(e8.w << 16); ef[7] = __uint_as_float(e8.w & 0xffff0000u);
    float4 r0 = *(const float4*)&rowsi[g * 8];
    float4 r1 = *(const float4*)&rowsi[g * 8 + 4];
    union { unsigned short us[8]; uint4 u4; } ko;
    ko.us[0] = f2bf(ef[0] * r0.x); ko.us[1] = f2bf(ef[1] * r0.y);
    ko.us[2] = f2bf(ef[2] * r0.z); ko.us[3] = f2bf(ef[3] * r0.w);
    ko.us[4] = f2bf(ef[4] * r1.x); ko.us[5] = f2bf(ef[5] * r1.y);
    ko.us[6] = f2bf(ef[6] * r1.z); ko.us[7] = f2bf(ef[7] * r1.w);
    size_t orow = ((size_t)b * DIMD + dl) * NTOK + n0 + g * 8;
    *(uint4*)(Kt + orow) = ko.u4;
    *(uint4*)(Qt + orow) = e8;                   // raw exp bits
    // colsum partial over this tile's 32 tokens for dim dl
    float cs = ((ef[0] + ef[1]) + (ef[2] + ef[3])) + ((ef[4] + ef[5]) + (ef[6] + ef[7]));
    cs += __shfl_xor(cs, 1, 64);
    cs += __shfl_xor(cs, 2, 64);
    if (g == 0)
      atomicAdd(csp + ((size_t)b * 32 + (tile >> 1)) * DIMD + dl, cs);
  }
}

// standalone GEMM (final epilogue)
template <int TMD, int TND, int EPI>
__global__ __launch_bounds__(256) void mfma_bt(
    const unsigned short* __restrict__ A, const unsigned short* __restrict__ B,
    void* __restrict__ Cout, int K, int lda, int ldb, int ldc, int ntx,
    long long sA, long long sB, long long sC,
    const float* __restrict__ wg, const float* __restrict__ b1v,
    const float* __restrict__ b2v, const float* __restrict__ xres) {
  __shared__ __align__(16) unsigned short As[2 * 64 * TMD * 64];
  __shared__ __align__(16) unsigned short Bs[2 * 64 * TND * 64];
  gemm_body<TMD, TND, EPI>(As, Bs, blockIdx.x, A, B, Cout, K, lda, ldb, ldc, ntx,
                           sA, sB, sC, wg, b1v, b2v, xres);
}

// S-gemm (both attentions in one launch when grid=576): blocks [0,288) do
// S_a = Kta . Qta^T * diag(cspa^-1); [288,576) do S_b -> Cb.
__global__ __launch_bounds__(256) void sgemm_s(
    const unsigned short* __restrict__ KtA, const unsigned short* __restrict__ QtA,
    const float* __restrict__ cspA,
    const unsigned short* __restrict__ KtB, const unsigned short* __restrict__ QtB,
    const float* __restrict__ cspB,
    unsigned short* __restrict__ Ca, unsigned short* __restrict__ Cb) {
  __shared__ __align__(16) unsigned short As[2 * 128 * 64];
  __shared__ __align__(16) unsigned short Bs[2 * 128 * 64];
  bool second = blockIdx.x >= 288;
  const unsigned short* A = second ? KtB : KtA;
  const unsigned short* B = second ? QtB : QtA;
  const float* csp = second ? cspB : cspA;
  unsigned short* C = second ? Cb : Ca;
  int blk = second ? (blockIdx.x - 288) : blockIdx.x;
  gemm_body<2, 2, 2>(As, Bs, blk, A, B, C, NTOK, NTOK, NTOK, 1536, 6,
                     768LL * NTOK, 768LL * NTOK, 768LL * 1536,
                     nullptr, csp, nullptr, nullptr);
}

// s2 (Bt = Wcat . Scat^T, 288 blocks, 128x128) + pack_x (6144 BW-bound blocks;
// must stay in this launch: xb aliases the Kt1 region, dead only after sgemm_s)
__global__ __launch_bounds__(256) void s2_packx_kernel(
    const unsigned short* __restrict__ Wcat, const unsigned short* __restrict__ Scat,
    unsigned short* __restrict__ Bt, const float* __restrict__ x,
    unsigned short* __restrict__ xb) {
  __shared__ __align__(16) unsigned short As[2 * 128 * 64];
  __shared__ __align__(16) unsigned short Bs[2 * 128 * 64];
  int blk = blockIdx.x;
  if (blk < 288) {
    gemm_body<2, 2, 0>(As, Bs, blk, Wcat, Scat, Bt, 1536, 1536, 1536, 768, 6,
                       0LL, 768LL * 1536, 768LL * 768,
                       nullptr, nullptr, nullptr, nullptr);
  } else {
    packx_body(blk - 288, x, xb);
  }
}

// ---------------------------------------------------------------------------
// launch
// ---------------------------------------------------------------------------
extern "C" void kernel_launch(void* const* d_in, const int* in_sizes, int n_in,
                              void* d_out, int out_size, void* d_ws, size_t ws_size,
                              hipStream_t stream) {
  const float* x  = (const float*)d_in[0];
  const float* x2 = (const float*)d_in[1];
  const float* x3 = (const float*)d_in[2];
  const float* W1 = (const float*)d_in[3];
  const float* b1 = (const float*)d_in[4];
  const float* W2 = (const float*)d_in[5];
  const float* b2 = (const float*)d_in[6];
  const float* w  = (const float*)d_in[7];
  float* out = (float*)d_out;
  char* ws = (char*)d_ws;

  dim3 blk(256);
  const bool merged = ws_size >= 123600896ull;

  if (merged) {
    // layout (bytes): Kt1 0 | Qt1 25165824 | Kt2 50331648 | Qt2 75497472 |
    // Scat 100663296 | Wcat 119537664 | csp1 121896960 | csp2 122683392 |
    // end 123469824. Bt aliases Kt1 (dead after sgemm_s); xb aliases Kt1+9437184.
    unsigned short* Kt1  = (unsigned short*)(ws + 0);
    unsigned short* Qt1  = (unsigned short*)(ws + 25165824);
    unsigned short* Kt2  = (unsigned short*)(ws + 50331648);
    unsigned short* Qt2  = (unsigned short*)(ws + 75497472);
    unsigned short* Scat = (unsigned short*)(ws + 100663296);
    unsigned short* Wcat = (unsigned short*)(ws + 119537664);
    float* csp1 = (float*)(ws + 121896960);
    float* csp2 = (float*)(ws + 122683392);
    unsigned short* Bt = (unsigned short*)(ws + 0);
    unsigned short* xb = (unsigned short*)(ws + 9437184);

    hipMemsetAsync(ws + 121896960, 0, 1572864, stream);   // zero csp1+csp2
    stage1_kernel<<<1600, blk, 0, stream>>>(x2, Kt1, Qt1, csp1,
                                            x3, Kt2, Qt2, csp2, 1024,
                                            W1, W2, Wcat, 576);
    sgemm_s<<<576, blk, 0, stream>>>(Kt1, Qt1, csp1, Kt2, Qt2, csp2, Scat, Scat + 768);
    s2_packx_kernel<<<6432, blk, 0, stream>>>(Wcat, Scat, Bt, x, xb);
    mfma_bt<2, 2, 1><<<768, blk, 0, stream>>>(xb, Bt, out, DIMD, DIMD, DIMD, DIMD, 6,
                                              (long long)NTOK * DIMD, 768LL * 768,
                                              (long long)NTOK * DIMD, w, b1, b2, x);
  } else {
    // sequential fallback within the proven 107 MB footprint:
    // Kt 0 | Qt 25165824 | Scat 50331648 | Bt 69206016 | xb 78643200 |
    // Wcat 103809024 (end 106168320). csp alias the Bt region (dead until s2).
    unsigned short* Kt   = (unsigned short*)(ws + 0);
    unsigned short* Qt   = (unsigned short*)(ws + 25165824);
    unsigned short* Scat = (unsigned short*)(ws + 50331648);
    unsigned short* Bt   = (unsigned short*)(ws + 69206016);
    float* csp1 = (float*)(ws + 69206016);
    float* csp2 = (float*)(ws + 69992448);
    unsigned short* xb   = (unsigned short*)(ws + 78643200);
    unsigned short* Wcat = (unsigned short*)(ws + 103809024);

    hipMemsetAsync(ws + 69206016, 0, 1572864, stream);    // zero csp1+csp2
    stage1_kernel<<<1088, blk, 0, stream>>>(x2, Kt, Qt, csp1,
                                            x2, Kt, Qt, csp1, 512,
                                            W1, W2, Wcat, 576);
    sgemm_s<<<288, blk, 0, stream>>>(Kt, Qt, csp1, Kt, Qt, csp1, Scat, Scat);
    stage1_kernel<<<512, blk, 0, stream>>>(x3, Kt, Qt, csp2,
                                           x3, Kt, Qt, csp2, 512,
                                           W1, W2, Wcat, 0);
    sgemm_s<<<288, blk, 0, stream>>>(Kt, Qt, csp2, Kt, Qt, csp2, Scat + 768, Scat + 768);
    s2_packx_kernel<<<6432, blk, 0, stream>>>(Wcat, Scat, Bt, x, xb);
    mfma_bt<2, 2, 1><<<768, blk, 0, stream>>>(xb, Bt, out, DIMD, DIMD, DIMD, DIMD, 6,
                                              (long long)NTOK * DIMD, 768LL * 768,
                                              (long long)NTOK * DIMD, w, b1, b2, x);
  }
}

// Round 5
// 328.031 us; speedup vs baseline: 1.0115x; 1.0115x over previous
//
#include <hip/hip_runtime.h>

// Problem constants
#define DIMD 768
#define NTOK 2048
#define NB   8

typedef __attribute__((ext_vector_type(8))) short bfrag8;
typedef __attribute__((ext_vector_type(4))) float accf4;

// float -> bf16 bits, round-to-nearest-even (finite inputs)
__device__ __forceinline__ unsigned short f2bf(float f) {
  unsigned u = __float_as_uint(f);
  return (unsigned short)((u + 0x7fffu + ((u >> 16) & 1u)) >> 16);
}

// async 16B global -> LDS (wave-uniform base + lane*16 semantics)
__device__ __forceinline__ void glds16(const void* g, void* l) {
  __builtin_amdgcn_global_load_lds(
      (const __attribute__((address_space(1))) void*)g,
      (__attribute__((address_space(3))) void*)l, 16, 0, 0);
}

// ---------------------------------------------------------------------------
// device bodies
// ---------------------------------------------------------------------------

// pack W1|W2 -> Wcat bf16 [768][1536]
__device__ __forceinline__ void packw_body(int blk, const float* __restrict__ W1,
                                           const float* __restrict__ W2,
                                           unsigned short* __restrict__ Wcat) {
  int gid = blk * 256 + threadIdx.x;           // one per 4 elems
  int r = gid / 192, c4 = (gid % 192) * 4;
  float4 a = *(const float4*)(W1 + (size_t)r * DIMD + c4);
  float4 b = *(const float4*)(W2 + (size_t)r * DIMD + c4);
  union { unsigned short us[4]; uint2 u2; } ra, rb;
  ra.us[0] = f2bf(a.x); ra.us[1] = f2bf(a.y); ra.us[2] = f2bf(a.z); ra.us[3] = f2bf(a.w);
  rb.us[0] = f2bf(b.x); rb.us[1] = f2bf(b.y); rb.us[2] = f2bf(b.z); rb.us[3] = f2bf(b.w);
  *(uint2*)(Wcat + (size_t)r * 1536 + c4) = ra.u2;
  *(uint2*)(Wcat + (size_t)r * 1536 + 768 + c4) = rb.u2;
}

// pack x -> bf16 (one thread per 8 floats)
__device__ __forceinline__ void packx_body(int blk, const float* __restrict__ x,
                                           unsigned short* __restrict__ xb) {
  size_t gid = (size_t)blk * 256 + threadIdx.x;
  const float4* x4 = (const float4*)x;
  float4 v0 = x4[gid * 2], v1 = x4[gid * 2 + 1];
  union { unsigned short us[8]; uint4 u4; } r;
  r.us[0] = f2bf(v0.x); r.us[1] = f2bf(v0.y); r.us[2] = f2bf(v0.z); r.us[3] = f2bf(v0.w);
  r.us[4] = f2bf(v1.x); r.us[5] = f2bf(v1.y); r.us[6] = f2bf(v1.z); r.us[7] = f2bf(v1.w);
  ((uint4*)xb)[gid] = r.u4;
}

// BT-format bf16 MFMA GEMM body: C[m][n] = sum_k A[m][k] * B[n][k]
// Tile (64*TMD) x (64*TND), 4 waves, BK=64, glds16 staging.
// Double-buffered LDS, prefetch-before-compute, one fused
// "s_waitcnt vmcnt(0); s_barrier" per K-step.
// LDS bank-conflict swizzle (both-sides-or-neither): LDS dest stays linear
// (glds16 requirement); the 16B slot within each row is permuted on the
// GLOBAL source side (scol) and identically on the fragment-read side.
// bid & 7 -> batch (XCD affinity).
// EPI 0: store bf16.
// EPI 1: f32 epilogue gate*acc + gate*(b1+b2) + x.
// EPI 2: bf16 store scaled by per-column inv-colsum (b1v = csp partials [b][64][768]).
template <int TMD, int TND, int EPI>
__device__ __forceinline__ void gemm_body(
    unsigned short* As, unsigned short* Bs, int bid,
    const unsigned short* __restrict__ A, const unsigned short* __restrict__ B,
    void* __restrict__ Cout, int K, int lda, int ldb, int ldc, int ntx,
    long long sA, long long sB, long long sC,
    const float* __restrict__ wg, const float* __restrict__ b1v,
    const float* __restrict__ b2v, const float* __restrict__ xres) {
  constexpr int TM = 64 * TMD, TN = 64 * TND;
  constexpr int ASZ = TM * 64, BSZ = TN * 64;  // shorts per LDS buffer
  __shared__ float csi[64 * TND];              // EPI==2: inv colsum per C column
  const int t = threadIdx.x, w = t >> 6, lane = t & 63;
  const int bz = bid & 7;
  const int r = bid >> 3;
  const int by = r / ntx, bx = r - by * ntx;
  const int m0 = by * TM, n0 = bx * TN;
  const unsigned short* Ab = A + (size_t)bz * sA;
  const unsigned short* Bb = B + (size_t)bz * sB;
  const int srow = lane >> 3;          // 0..7 (row within 8-row chunk)
  // swizzled 16B slot: slot' = slot ^ (row&7)
  const int scol = (((lane & 7) ^ (lane >> 3)) * 8);

  auto stage = [&](int buf, int k0) {
    unsigned short* Ad = As + buf * ASZ;
    unsigned short* Bd = Bs + buf * BSZ;
#pragma unroll
    for (int l = 0; l < 2 * TND; ++l) {
      int chunk = l * 4 + w;
      int row = chunk * 8 + srow;
      glds16(Bb + (size_t)(n0 + row) * ldb + k0 + scol,
             (char*)Bd + chunk * 1024 + lane * 16);
    }
#pragma unroll
    for (int l = 0; l < 2 * TMD; ++l) {
      int chunk = l * 4 + w;
      int row = chunk * 8 + srow;
      glds16(Ab + (size_t)(m0 + row) * lda + k0 + scol,
             (char*)Ad + chunk * 1024 + lane * 16);
    }
  };

  stage(0, 0);

  if (EPI == 2) {
    // merge 64 colsum partials -> 1/sum for this block's output columns
    for (int c = t; c < TN; c += 256) {
      const float* cp = b1v + (size_t)bz * 64 * DIMD + n0 + c;
      float s = 0.f;
#pragma unroll
      for (int p = 0; p < 64; ++p) s += cp[(size_t)p * DIMD];
      csi[c] = 1.0f / s;
    }
  }

  accf4 zero = {0.f, 0.f, 0.f, 0.f};
  accf4 acc[2 * TMD][2 * TND];
#pragma unroll
  for (int i = 0; i < 2 * TMD; ++i)
#pragma unroll
    for (int j = 0; j < 2 * TND; ++j) acc[i][j] = zero;

  const int wm = (w & 1) * (32 * TMD), wn = (w >> 1) * (32 * TND);
  const int lm = lane & 15, qd = lane >> 4;
  const int lsw = (lm & 7) << 3;       // read-side swizzle XOR (in shorts)

  // drains stage(0) (syncthreads implies vmcnt(0)+lgkmcnt(0)) and makes csi visible
  __syncthreads();

  const int nt = K / 64;
  int cur = 0;
#pragma unroll 2
  for (int tt = 0; tt < nt; ++tt) {
    if (tt + 1 < nt) stage(cur ^ 1, (tt + 1) * 64);
    const unsigned short* Ar = As + cur * ASZ;
    const unsigned short* Br = Bs + cur * BSZ;
#pragma unroll
    for (int kc = 0; kc < 2; ++kc) {
      bfrag8 av[2 * TMD], bv[2 * TND];
      const int kslot = (((kc << 2) | qd) << 3) ^ lsw;   // swizzled 16B slot
#pragma unroll
      for (int i = 0; i < 2 * TMD; ++i)
        av[i] = *(const bfrag8*)(Ar + (wm + i * 16 + lm) * 64 + kslot);
#pragma unroll
      for (int j = 0; j < 2 * TND; ++j)
        bv[j] = *(const bfrag8*)(Br + (wn + j * 16 + lm) * 64 + kslot);
      __builtin_amdgcn_s_setprio(1);
#pragma unroll
      for (int i = 0; i < 2 * TMD; ++i)
#pragma unroll
        for (int j = 0; j < 2 * TND; ++j)
          acc[i][j] = __builtin_amdgcn_mfma_f32_16x16x32_bf16(av[i], bv[j], acc[i][j], 0, 0, 0);
      __builtin_amdgcn_s_setprio(0);
    }
    if (tt + 1 < nt) {
      // fused: wait own stage loads, then workgroup barrier. All ds_reads of
      // buf[cur] were consumed by MFMAs above, so buf[cur] is free to restage.
      asm volatile("s_waitcnt vmcnt(0)\n\ts_barrier" ::: "memory");
    }
    cur ^= 1;
  }

  if (EPI == 0) {
    unsigned short* Cb = (unsigned short*)Cout + (size_t)bz * sC;
#pragma unroll
    for (int i = 0; i < 2 * TMD; ++i)
#pragma unroll
      for (int j = 0; j < 2 * TND; ++j) {
        int col = n0 + wn + j * 16 + lm;
#pragma unroll
        for (int rr = 0; rr < 4; ++rr) {
          int row = m0 + wm + i * 16 + qd * 4 + rr;
          Cb[(size_t)row * ldc + col] = f2bf(acc[i][j][rr]);
        }
      }
  } else if (EPI == 1) {
    float gate = 1.f / (1.f + __expf(-wg[0]));
    float* Co = (float*)Cout + (size_t)bz * sC;
    const float* Xr = xres + (size_t)bz * sC;
#pragma unroll
    for (int j = 0; j < 2 * TND; ++j) {
      int col = n0 + wn + j * 16 + lm;
      float gb = gate * (b1v[col] + b2v[col]);
#pragma unroll
      for (int i = 0; i < 2 * TMD; ++i)
#pragma unroll
        for (int rr = 0; rr < 4; ++rr) {
          int row = m0 + wm + i * 16 + qd * 4 + rr;
          size_t idx = (size_t)row * ldc + col;
          Co[idx] = gate * acc[i][j][rr] + gb + Xr[idx];
        }
    }
  } else {
    unsigned short* Cb = (unsigned short*)Cout + (size_t)bz * sC;
#pragma unroll
    for (int j = 0; j < 2 * TND; ++j) {
      int lc = wn + j * 16 + lm;
      int col = n0 + lc;
      float ci = csi[lc];
#pragma unroll
      for (int i = 0; i < 2 * TMD; ++i)
#pragma unroll
        for (int rr = 0; rr < 4; ++rr) {
          int row = m0 + wm + i * 16 + qd * 4 + rr;
          Cb[(size_t)row * ldc + col] = f2bf(acc[i][j][rr] * ci);
        }
    }
  }
}

// ---------------------------------------------------------------------------
// kernel 1: rowcol — one coalesced pass over x2|x3 computing BOTH softmax
// normalizers: rsf = sqrt(1/rowsum(exp)) per token (feature-axis softmax),
// and csp[b][64][768] = per-32-token-tile colsum partials of raw exp
// (token-axis softmax, merged in the S-gemm epilogue). Tiny LDS (12 KB)
// -> high occupancy, streams at HBM rate. packw rides along.
// blocks [0,1024): sel=blk>>9, b=(blk>>6)&7, tile32=blk&63 (32 tokens each)
// blocks [1024, 1024+npw): packw
// ---------------------------------------------------------------------------
__global__ __launch_bounds__(256) void rowcol_kernel(
    const float* __restrict__ x2, const float* __restrict__ x3,
    float* __restrict__ csp1, float* __restrict__ csp2,
    float* __restrict__ rsf,
    const float* __restrict__ W1, const float* __restrict__ W2,
    unsigned short* __restrict__ Wcat, int npw) {
  int blk = blockIdx.x;
  if (blk >= 1024) {
    if (blk < 1024 + npw) packw_body(blk - 1024, W1, W2, Wcat);
    return;
  }
  const int sel = blk >> 9, b = (blk >> 6) & 7, tile = blk & 63;
  const float* xin = sel ? x3 : x2;
  float* csp = sel ? csp2 : csp1;
  float* rso = rsf + (size_t)sel * NB * NTOK + (size_t)b * NTOK + tile * 32;
  const float* xb_ = xin + ((size_t)b * NTOK + tile * 32) * DIMD;
  const int t = threadIdx.x, w = t >> 6, lane = t & 63;
  __shared__ float cred[4][DIMD];

  const int d0 = lane * 12;
  float cs[12];
#pragma unroll
  for (int i = 0; i < 12; ++i) cs[i] = 0.f;

#pragma unroll
  for (int v = 0; v < 8; ++v) {
    int tok = w * 8 + v;
    const float* row = xb_ + (size_t)tok * DIMD + d0;
    float4 a = *(const float4*)(row);
    float4 c = *(const float4*)(row + 4);
    float4 d = *(const float4*)(row + 8);
    float e[12];
    e[0] = __expf(a.x); e[1] = __expf(a.y); e[2] = __expf(a.z); e[3] = __expf(a.w);
    e[4] = __expf(c.x); e[5] = __expf(c.y); e[6] = __expf(c.z); e[7] = __expf(c.w);
    e[8] = __expf(d.x); e[9] = __expf(d.y); e[10] = __expf(d.z); e[11] = __expf(d.w);
    float rp = 0.f;
#pragma unroll
    for (int i = 0; i < 12; ++i) { rp += e[i]; cs[i] += e[i]; }
#pragma unroll
    for (int off = 32; off; off >>= 1) rp += __shfl_xor(rp, off, 64);
    if (lane == 0) rso[tok] = sqrtf(1.0f / rp);
  }
  // cross-wave colsum reduce
#pragma unroll
  for (int i = 0; i < 12; ++i) cred[w][d0 + i] = cs[i];
  __syncthreads();
#pragma unroll
  for (int i = 0; i < 3; ++i) {
    int d = t * 3 + i;
    float s = cred[0][d] + cred[1][d] + cred[2][d] + cred[3][d];
    csp[((size_t)b * 64 + tile) * DIMD + d] = s;
  }
}

// ---------------------------------------------------------------------------
// kernel 2: ft — build Ft[b][D][N] = transpose(exp(x) * sqrt(1/rowsum)).
// S = Ft.Ft^T is symmetric (F = E*sqrt(rsi) absorbs the feature-softmax
// normalizer symmetrically), so ONE buffer replaces Kt+Qt: stage writes
// halve and the S-gemm reads the same buffer for both operands.
// Block = 64 tokens x 192 dims: LDS 27.6 KB -> ~5 blocks/CU; x re-read is
// L3-hot (kernel 1 just streamed it); writes are 128 B contiguous chunks.
// Grid 2048: sel=blk>>10; b=(lb>>7); ntile=(lb&127)>>2; dc=lb&3.
// ---------------------------------------------------------------------------
__global__ __launch_bounds__(256) void ft_kernel(
    const float* __restrict__ x2, const float* __restrict__ x3,
    const float* __restrict__ rsf,
    unsigned short* __restrict__ Ft1, unsigned short* __restrict__ Ft2) {
  __shared__ __align__(16) unsigned short etile[192 * 72];
  const int blk = blockIdx.x;
  const int sel = blk >> 10, lb = blk & 1023;
  const int b = lb >> 7, rr = lb & 127, ntile = rr >> 2, dc = rr & 3;
  const float* xin = sel ? x3 : x2;
  unsigned short* Ft = sel ? Ft2 : Ft1;
  const float* rsv = rsf + (size_t)sel * NB * NTOK + (size_t)b * NTOK + ntile * 64;
  const int t = threadIdx.x;

  const int tok = t >> 2, q4 = t & 3;            // 4 threads/token, 48 dims each
  const float* row = xin + ((size_t)b * NTOK + ntile * 64 + tok) * DIMD + dc * 192 + q4 * 48;
  const float fsc = rsv[tok];
#pragma unroll
  for (int j = 0; j < 12; ++j) {
    float4 v = *(const float4*)(row + j * 4);
    int dl = q4 * 48 + j * 4;
    etile[(dl + 0) * 72 + tok] = f2bf(__expf(v.x) * fsc);
    etile[(dl + 1) * 72 + tok] = f2bf(__expf(v.y) * fsc);
    etile[(dl + 2) * 72 + tok] = f2bf(__expf(v.z) * fsc);
    etile[(dl + 3) * 72 + tok] = f2bf(__expf(v.w) * fsc);
  }
  __syncthreads();
#pragma unroll
  for (int k = 0; k < 6; ++k) {
    int dl = (t >> 3) + k * 32;                  // 0..191
    int g = t & 7;                               // 8 lanes x 16B = 128B/row
    uint4 e8 = *(const uint4*)(etile + dl * 72 + g * 8);
    *(uint4*)(Ft + ((size_t)b * DIMD + dc * 192 + dl) * NTOK + ntile * 64 + g * 8) = e8;
  }
}

// standalone GEMM (final epilogue)
template <int TMD, int TND, int EPI>
__global__ __launch_bounds__(256) void mfma_bt(
    const unsigned short* __restrict__ A, const unsigned short* __restrict__ B,
    void* __restrict__ Cout, int K, int lda, int ldb, int ldc, int ntx,
    long long sA, long long sB, long long sC,
    const float* __restrict__ wg, const float* __restrict__ b1v,
    const float* __restrict__ b2v, const float* __restrict__ xres) {
  __shared__ __align__(16) unsigned short As[2 * 64 * TMD * 64];
  __shared__ __align__(16) unsigned short Bs[2 * 64 * TND * 64];
  gemm_body<TMD, TND, EPI>(As, Bs, blockIdx.x, A, B, Cout, K, lda, ldb, ldc, ntx,
                           sA, sB, sC, wg, b1v, b2v, xres);
}

// S-gemm (both attentions, one launch): blocks [0,288) S_a = Ft1.Ft1^T
// * diag(colsum^-1) -> Ca; [288,576) S_b = Ft2.Ft2^T -> Cb. A==B buffer.
__global__ __launch_bounds__(256) void sgemm_s(
    const unsigned short* __restrict__ Ft1, const float* __restrict__ csp1,
    const unsigned short* __restrict__ Ft2, const float* __restrict__ csp2,
    unsigned short* __restrict__ Ca, unsigned short* __restrict__ Cb) {
  __shared__ __align__(16) unsigned short As[2 * 128 * 64];
  __shared__ __align__(16) unsigned short Bs[2 * 128 * 64];
  bool second = blockIdx.x >= 288;
  const unsigned short* F = second ? Ft2 : Ft1;
  const float* csp = second ? csp2 : csp1;
  unsigned short* C = second ? Cb : Ca;
  int blk = second ? (blockIdx.x - 288) : blockIdx.x;
  gemm_body<2, 2, 2>(As, Bs, blk, F, F, C, NTOK, NTOK, NTOK, 1536, 6,
                     768LL * NTOK, 768LL * NTOK, 768LL * 1536,
                     nullptr, csp, nullptr, nullptr);
}

// s2 (Bt = Wcat . Scat^T, 288 blocks, 128x128) + pack_x (6144 BW-bound blocks;
// xb aliases the Ft region, dead only after sgemm_s -> must stay here)
__global__ __launch_bounds__(256) void s2_packx_kernel(
    const unsigned short* __restrict__ Wcat, const unsigned short* __restrict__ Scat,
    unsigned short* __restrict__ Bt, const float* __restrict__ x,
    unsigned short* __restrict__ xb) {
  __shared__ __align__(16) unsigned short As[2 * 128 * 64];
  __shared__ __align__(16) unsigned short Bs[2 * 128 * 64];
  int blk = blockIdx.x;
  if (blk < 288) {
    gemm_body<2, 2, 0>(As, Bs, blk, Wcat, Scat, Bt, 1536, 1536, 1536, 768, 6,
                       0LL, 768LL * 1536, 768LL * 768,
                       nullptr, nullptr, nullptr, nullptr);
  } else {
    packx_body(blk - 288, x, xb);
  }
}

// ---------------------------------------------------------------------------
// launch
// ---------------------------------------------------------------------------
extern "C" void kernel_launch(void* const* d_in, const int* in_sizes, int n_in,
                              void* d_out, int out_size, void* d_ws, size_t ws_size,
                              hipStream_t stream) {
  const float* x  = (const float*)d_in[0];
  const float* x2 = (const float*)d_in[1];
  const float* x3 = (const float*)d_in[2];
  const float* W1 = (const float*)d_in[3];
  const float* b1 = (const float*)d_in[4];
  const float* W2 = (const float*)d_in[5];
  const float* b2 = (const float*)d_in[6];
  const float* w  = (const float*)d_in[7];
  float* out = (float*)d_out;
  char* ws = (char*)d_ws;

  // workspace layout (bytes), total 74842112 (fits the >=107MB harness ws):
  // Ft1 0 (25165824) | Ft2 25165824 (25165824) | Scat 50331648 (18874368) |
  // Wcat 69206016 (2359296) | csp1 71565312 (1572864) | csp2 73138176 (1572864) |
  // rsf 74711040 (131072).
  // Bt aliases Ft1 (dead after sgemm_s); xb aliases Ft1+9437184.
  unsigned short* Ft1  = (unsigned short*)(ws + 0);
  unsigned short* Ft2  = (unsigned short*)(ws + 25165824);
  unsigned short* Scat = (unsigned short*)(ws + 50331648);
  unsigned short* Wcat = (unsigned short*)(ws + 69206016);
  float* csp1 = (float*)(ws + 71565312);
  float* csp2 = (float*)(ws + 73138176);
  float* rsf  = (float*)(ws + 74711040);
  unsigned short* Bt = (unsigned short*)(ws + 0);
  unsigned short* xb = (unsigned short*)(ws + 9437184);

  dim3 blk(256);

  // 1: rowsum + colsum partials of exp(x2),exp(x3) + pack_w
  rowcol_kernel<<<1600, blk, 0, stream>>>(x2, x3, csp1, csp2, rsf, W1, W2, Wcat, 576);
  // 2: Ft = (exp(x) * sqrt(rowsum_inv))^T, bf16 [b][D][N]
  ft_kernel<<<2048, blk, 0, stream>>>(x2, x3, rsf, Ft1, Ft2);
  // 3: Scat = Ft.Ft^T * diag(colsum^-1), both attentions
  sgemm_s<<<576, blk, 0, stream>>>(Ft1, csp1, Ft2, csp2, Scat, Scat + 768);
  // 4: Bt = Wcat . Scat^T (K=1536) + pack x->bf16
  s2_packx_kernel<<<6432, blk, 0, stream>>>(Wcat, Scat, Bt, x, xb);
  // 5: out = gate * xb.Bt^T + gate*(b1+b2) + x
  mfma_bt<2, 2, 1><<<768, blk, 0, stream>>>(xb, Bt, out, DIMD, DIMD, DIMD, DIMD, 6,
                                            (long long)NTOK * DIMD, 768LL * 768,
                                            (long long)NTOK * DIMD, w, b1, b2, x);
}

// Round 6
// 308.753 us; speedup vs baseline: 1.0746x; 1.0624x over previous
//
#include <hip/hip_runtime.h>

// Problem constants
#define DIMD 768
#define NTOK 2048
#define NB   8

typedef __attribute__((ext_vector_type(8))) short bfrag8;
typedef __attribute__((ext_vector_type(4))) float accf4;

// float -> bf16 bits, round-to-nearest-even (finite inputs)
__device__ __forceinline__ unsigned short f2bf(float f) {
  unsigned u = __float_as_uint(f);
  return (unsigned short)((u + 0x7fffu + ((u >> 16) & 1u)) >> 16);
}

// async 16B global -> LDS (wave-uniform base + lane*16 semantics)
__device__ __forceinline__ void glds16(const void* g, void* l) {
  __builtin_amdgcn_global_load_lds(
      (const __attribute__((address_space(1))) void*)g,
      (__attribute__((address_space(3))) void*)l, 16, 0, 0);
}

// ---------------------------------------------------------------------------
// device bodies
// ---------------------------------------------------------------------------

// pack W1|W2 -> Wcat bf16 [768][1536]
__device__ __forceinline__ void packw_body(int blk, const float* __restrict__ W1,
                                           const float* __restrict__ W2,
                                           unsigned short* __restrict__ Wcat) {
  int gid = blk * 256 + threadIdx.x;           // one per 4 elems
  int r = gid / 192, c4 = (gid % 192) * 4;
  float4 a = *(const float4*)(W1 + (size_t)r * DIMD + c4);
  float4 b = *(const float4*)(W2 + (size_t)r * DIMD + c4);
  union { unsigned short us[4]; uint2 u2; } ra, rb;
  ra.us[0] = f2bf(a.x); ra.us[1] = f2bf(a.y); ra.us[2] = f2bf(a.z); ra.us[3] = f2bf(a.w);
  rb.us[0] = f2bf(b.x); rb.us[1] = f2bf(b.y); rb.us[2] = f2bf(b.z); rb.us[3] = f2bf(b.w);
  *(uint2*)(Wcat + (size_t)r * 1536 + c4) = ra.u2;
  *(uint2*)(Wcat + (size_t)r * 1536 + 768 + c4) = rb.u2;
}

// pack x -> bf16 (one thread per 8 floats)
__device__ __forceinline__ void packx_body(int blk, const float* __restrict__ x,
                                           unsigned short* __restrict__ xb) {
  size_t gid = (size_t)blk * 256 + threadIdx.x;
  const float4* x4 = (const float4*)x;
  float4 v0 = x4[gid * 2], v1 = x4[gid * 2 + 1];
  union { unsigned short us[8]; uint4 u4; } r;
  r.us[0] = f2bf(v0.x); r.us[1] = f2bf(v0.y); r.us[2] = f2bf(v0.z); r.us[3] = f2bf(v0.w);
  r.us[4] = f2bf(v1.x); r.us[5] = f2bf(v1.y); r.us[6] = f2bf(v1.z); r.us[7] = f2bf(v1.w);
  ((uint4*)xb)[gid] = r.u4;
}

// BT-format bf16 MFMA GEMM body: C[m][n] = sum_k A[m][k] * B[n][k]
// Tile (64*TMD) x (64*TND), 4 waves, BK=64, glds16 staging.
// Double-buffered LDS, prefetch-before-compute, one fused
// "s_waitcnt vmcnt(0); s_barrier" per K-step.
// LDS bank-conflict swizzle (both-sides-or-neither): LDS dest stays linear
// (glds16 requirement); the 16B slot within each row is permuted on the
// GLOBAL source side (scol) and identically on the fragment-read side.
// bid & 7 -> batch (XCD affinity).
// EPI 0: store bf16.
// EPI 1: f32 epilogue gate*acc + gate*(b1+b2) + x.
// EPI 2: SYMMETRIC bf16 store (requires TMD==TND==2, A==B==F, square tri
//        tile grid): C[m][n] = acc*civ[n]; for off-diag tiles additionally
//        C[n][m] = acc*civ[m] via LDS-staged transpose (single rounding per
//        element; b1v = civ = precomputed 1/colsum per [b][768]).
template <int TMD, int TND, int EPI>
__device__ __forceinline__ void gemm_body(
    unsigned short* As, unsigned short* Bs, int bid,
    const unsigned short* __restrict__ A, const unsigned short* __restrict__ B,
    void* __restrict__ Cout, int K, int lda, int ldb, int ldc, int ntx,
    long long sA, long long sB, long long sC,
    const float* __restrict__ wg, const float* __restrict__ b1v,
    const float* __restrict__ b2v, const float* __restrict__ xres) {
  constexpr int TM = 64 * TMD, TN = 64 * TND;
  constexpr int ASZ = TM * 64, BSZ = TN * 64;  // shorts per LDS buffer
  __shared__ float csi[64 * TND];              // EPI==2: 1/colsum for block cols
  __shared__ float csir[64 * TMD];             // EPI==2: 1/colsum for block rows
  const int t = threadIdx.x, w = t >> 6, lane = t & 63;
  const int bz = bid & 7;
  const int r = bid >> 3;
  const int by = r / ntx, bx = r - by * ntx;
  const int m0 = by * TM, n0 = bx * TN;
  const unsigned short* Ab = A + (size_t)bz * sA;
  const unsigned short* Bb = B + (size_t)bz * sB;
  const int srow = lane >> 3;          // 0..7 (row within 8-row chunk)
  // swizzled 16B slot: slot' = slot ^ (row&7)
  const int scol = (((lane & 7) ^ (lane >> 3)) * 8);

  auto stage = [&](int buf, int k0) {
    unsigned short* Ad = As + buf * ASZ;
    unsigned short* Bd = Bs + buf * BSZ;
#pragma unroll
    for (int l = 0; l < 2 * TND; ++l) {
      int chunk = l * 4 + w;
      int row = chunk * 8 + srow;
      glds16(Bb + (size_t)(n0 + row) * ldb + k0 + scol,
             (char*)Bd + chunk * 1024 + lane * 16);
    }
#pragma unroll
    for (int l = 0; l < 2 * TMD; ++l) {
      int chunk = l * 4 + w;
      int row = chunk * 8 + srow;
      glds16(Ab + (size_t)(m0 + row) * lda + k0 + scol,
             (char*)Ad + chunk * 1024 + lane * 16);
    }
  };

  stage(0, 0);

  if (EPI == 2) {
    // b1v = civ[b][768] (already inverted)
    for (int c = t; c < TN; c += 256) csi[c] = b1v[(size_t)bz * DIMD + n0 + c];
    for (int c = t; c < TM; c += 256) csir[c] = b1v[(size_t)bz * DIMD + m0 + c];
  }

  accf4 zero = {0.f, 0.f, 0.f, 0.f};
  accf4 acc[2 * TMD][2 * TND];
#pragma unroll
  for (int i = 0; i < 2 * TMD; ++i)
#pragma unroll
    for (int j = 0; j < 2 * TND; ++j) acc[i][j] = zero;

  const int wm = (w & 1) * (32 * TMD), wn = (w >> 1) * (32 * TND);
  const int lm = lane & 15, qd = lane >> 4;
  const int lsw = (lm & 7) << 3;       // read-side swizzle XOR (in shorts)

  // drains stage(0) (syncthreads implies vmcnt(0)+lgkmcnt(0)) and makes csi visible
  __syncthreads();

  const int nt = K / 64;
  int cur = 0;
#pragma unroll 2
  for (int tt = 0; tt < nt; ++tt) {
    if (tt + 1 < nt) stage(cur ^ 1, (tt + 1) * 64);
    const unsigned short* Ar = As + cur * ASZ;
    const unsigned short* Br = Bs + cur * BSZ;
#pragma unroll
    for (int kc = 0; kc < 2; ++kc) {
      bfrag8 av[2 * TMD], bv[2 * TND];
      const int kslot = (((kc << 2) | qd) << 3) ^ lsw;   // swizzled 16B slot
#pragma unroll
      for (int i = 0; i < 2 * TMD; ++i)
        av[i] = *(const bfrag8*)(Ar + (wm + i * 16 + lm) * 64 + kslot);
#pragma unroll
      for (int j = 0; j < 2 * TND; ++j)
        bv[j] = *(const bfrag8*)(Br + (wn + j * 16 + lm) * 64 + kslot);
      __builtin_amdgcn_s_setprio(1);
#pragma unroll
      for (int i = 0; i < 2 * TMD; ++i)
#pragma unroll
        for (int j = 0; j < 2 * TND; ++j)
          acc[i][j] = __builtin_amdgcn_mfma_f32_16x16x32_bf16(av[i], bv[j], acc[i][j], 0, 0, 0);
      __builtin_amdgcn_s_setprio(0);
    }
    if (tt + 1 < nt) {
      // fused: wait own stage loads, then workgroup barrier. All ds_reads of
      // buf[cur] were consumed by MFMAs above, so buf[cur] is free to restage.
      asm volatile("s_waitcnt vmcnt(0)\n\ts_barrier" ::: "memory");
    }
    cur ^= 1;
  }

  if (EPI == 0) {
    unsigned short* Cb = (unsigned short*)Cout + (size_t)bz * sC;
#pragma unroll
    for (int i = 0; i < 2 * TMD; ++i)
#pragma unroll
      for (int j = 0; j < 2 * TND; ++j) {
        int col = n0 + wn + j * 16 + lm;
#pragma unroll
        for (int rr = 0; rr < 4; ++rr) {
          int row = m0 + wm + i * 16 + qd * 4 + rr;
          Cb[(size_t)row * ldc + col] = f2bf(acc[i][j][rr]);
        }
      }
  } else if (EPI == 1) {
    float gate = 1.f / (1.f + __expf(-wg[0]));
    float* Co = (float*)Cout + (size_t)bz * sC;
    const float* Xr = xres + (size_t)bz * sC;
#pragma unroll
    for (int j = 0; j < 2 * TND; ++j) {
      int col = n0 + wn + j * 16 + lm;
      float gb = gate * (b1v[col] + b2v[col]);
#pragma unroll
      for (int i = 0; i < 2 * TMD; ++i)
#pragma unroll
        for (int rr = 0; rr < 4; ++rr) {
          int row = m0 + wm + i * 16 + qd * 4 + rr;
          size_t idx = (size_t)row * ldc + col;
          Co[idx] = gate * acc[i][j][rr] + gb + Xr[idx];
        }
    }
  } else {
    unsigned short* Cb = (unsigned short*)Cout + (size_t)bz * sC;
    // normal triangle write: S~[row][col] = acc * civ[col]
#pragma unroll
    for (int j = 0; j < 2 * TND; ++j) {
      int lc = wn + j * 16 + lm;
      int col = n0 + lc;
      float ci = csi[lc];
#pragma unroll
      for (int i = 0; i < 2 * TMD; ++i)
#pragma unroll
        for (int rr = 0; rr < 4; ++rr) {
          int row = m0 + wm + i * 16 + qd * 4 + rr;
          Cb[(size_t)row * ldc + col] = f2bf(acc[i][j][rr] * ci);
        }
    }
    if (m0 != n0) {
      // mirror tile: S~[col][row] = acc * civ[row], staged through LDS
      // (As is dead). XOR swizzle (lr^((lc&7)<<4)) keeps writes ~conflict-free
      // and reads at the 8-words/bank structural minimum.
      unsigned short* mir = As;          // 128*128 bf16 = 32 KB
      __syncthreads();                   // all MFMA ds_reads done
#pragma unroll
      for (int i = 0; i < 2 * TMD; ++i) {
        int lr0 = wm + i * 16 + qd * 4;  // multiple of 4
#pragma unroll
        for (int j = 0; j < 2 * TND; ++j) {
          int lc = wn + j * 16 + lm;
          int sw = (lc & 7) << 4;
          union { unsigned short us[4]; uint2 u2; } p;
#pragma unroll
          for (int rr = 0; rr < 4; ++rr)
            p.us[rr] = f2bf(acc[i][j][rr] * csir[lr0 + rr]);
          *(uint2*)&mir[lc * 128 + ((lr0) ^ sw)] = p.u2;
        }
      }
      __syncthreads();
      int e = t >> 1;                    // 0..127: mirror row (= orig col)
#pragma unroll
      for (int k = 0; k < 8; ++k) {
        int d0 = (((t & 1) << 3) + k) << 3;   // 0..120, step 8
        uint4 v = *(const uint4*)&mir[e * 128 + (d0 ^ ((e & 7) << 4))];
        *(uint4*)&Cb[(size_t)(n0 + e) * ldc + m0 + d0] = v;
      }
    }
  }
}

// ---------------------------------------------------------------------------
// kernel 1: rowcol — one coalesced pass over x2|x3 computing BOTH softmax
// normalizers: rsf = sqrt(1/rowsum(exp)) per token (feature-axis softmax),
// and csp[b][64][768] = per-32-token-tile colsum partials of raw exp
// (token-axis softmax). Tiny LDS -> high occupancy. packw rides along.
// ---------------------------------------------------------------------------
__global__ __launch_bounds__(256) void rowcol_kernel(
    const float* __restrict__ x2, const float* __restrict__ x3,
    float* __restrict__ csp1, float* __restrict__ csp2,
    float* __restrict__ rsf,
    const float* __restrict__ W1, const float* __restrict__ W2,
    unsigned short* __restrict__ Wcat, int npw) {
  int blk = blockIdx.x;
  if (blk >= 1024) {
    if (blk < 1024 + npw) packw_body(blk - 1024, W1, W2, Wcat);
    return;
  }
  const int sel = blk >> 9, b = (blk >> 6) & 7, tile = blk & 63;
  const float* xin = sel ? x3 : x2;
  float* csp = sel ? csp2 : csp1;
  float* rso = rsf + (size_t)sel * NB * NTOK + (size_t)b * NTOK + tile * 32;
  const float* xb_ = xin + ((size_t)b * NTOK + tile * 32) * DIMD;
  const int t = threadIdx.x, w = t >> 6, lane = t & 63;
  __shared__ float cred[4][DIMD];

  const int d0 = lane * 12;
  float cs[12];
#pragma unroll
  for (int i = 0; i < 12; ++i) cs[i] = 0.f;

#pragma unroll
  for (int v = 0; v < 8; ++v) {
    int tok = w * 8 + v;
    const float* row = xb_ + (size_t)tok * DIMD + d0;
    float4 a = *(const float4*)(row);
    float4 c = *(const float4*)(row + 4);
    float4 d = *(const float4*)(row + 8);
    float e[12];
    e[0] = __expf(a.x); e[1] = __expf(a.y); e[2] = __expf(a.z); e[3] = __expf(a.w);
    e[4] = __expf(c.x); e[5] = __expf(c.y); e[6] = __expf(c.z); e[7] = __expf(c.w);
    e[8] = __expf(d.x); e[9] = __expf(d.y); e[10] = __expf(d.z); e[11] = __expf(d.w);
    float rp = 0.f;
#pragma unroll
    for (int i = 0; i < 12; ++i) { rp += e[i]; cs[i] += e[i]; }
#pragma unroll
    for (int off = 32; off; off >>= 1) rp += __shfl_xor(rp, off, 64);
    if (lane == 0) rso[tok] = sqrtf(1.0f / rp);
  }
  // cross-wave colsum reduce
#pragma unroll
  for (int i = 0; i < 12; ++i) cred[w][d0 + i] = cs[i];
  __syncthreads();
#pragma unroll
  for (int i = 0; i < 3; ++i) {
    int d = t * 3 + i;
    float s = cred[0][d] + cred[1][d] + cred[2][d] + cred[3][d];
    csp[((size_t)b * 64 + tile) * DIMD + d] = s;
  }
}

// ---------------------------------------------------------------------------
// kernel 2: ft — build Ft[b][D][N] = transpose(exp(x) * sqrt(1/rowsum)).
// S = Ft.Ft^T symmetric -> one buffer serves both GEMM operands.
// Blocks [2048, 2096): colsum finalize rider: civ[sel][b][d] = 1/sum(csp).
// ---------------------------------------------------------------------------
__global__ __launch_bounds__(256) void ft_kernel(
    const float* __restrict__ x2, const float* __restrict__ x3,
    const float* __restrict__ rsf,
    unsigned short* __restrict__ Ft1, unsigned short* __restrict__ Ft2,
    const float* __restrict__ csp1, const float* __restrict__ csp2,
    float* __restrict__ civ1, float* __restrict__ civ2) {
  const int blk = blockIdx.x;
  if (blk >= 2048) {
    int idx = (blk - 2048) * 256 + threadIdx.x;  // 0..12287 = sel*6144 + b*768 + d
    int sel = idx / 6144, rem = idx - sel * 6144;
    int b = rem / DIMD, d = rem - b * DIMD;
    const float* csp = sel ? csp2 : csp1;
    float s = 0.f;
    const float* p = csp + (size_t)b * 64 * DIMD + d;
#pragma unroll 8
    for (int q = 0; q < 64; ++q) s += p[(size_t)q * DIMD];
    (sel ? civ2 : civ1)[rem] = 1.0f / s;
    return;
  }
  __shared__ __align__(16) unsigned short etile[192 * 72];
  const int sel = blk >> 10, lb = blk & 1023;
  const int b = lb >> 7, rr = lb & 127, ntile = rr >> 2, dc = rr & 3;
  const float* xin = sel ? x3 : x2;
  unsigned short* Ft = sel ? Ft2 : Ft1;
  const float* rsv = rsf + (size_t)sel * NB * NTOK + (size_t)b * NTOK + ntile * 64;
  const int t = threadIdx.x;

  const int tok = t >> 2, q4 = t & 3;            // 4 threads/token, 48 dims each
  const float* row = xin + ((size_t)b * NTOK + ntile * 64 + tok) * DIMD + dc * 192 + q4 * 48;
  const float fsc = rsv[tok];
#pragma unroll
  for (int j = 0; j < 12; ++j) {
    float4 v = *(const float4*)(row + j * 4);
    int dl = q4 * 48 + j * 4;
    etile[(dl + 0) * 72 + tok] = f2bf(__expf(v.x) * fsc);
    etile[(dl + 1) * 72 + tok] = f2bf(__expf(v.y) * fsc);
    etile[(dl + 2) * 72 + tok] = f2bf(__expf(v.z) * fsc);
    etile[(dl + 3) * 72 + tok] = f2bf(__expf(v.w) * fsc);
  }
  __syncthreads();
#pragma unroll
  for (int k = 0; k < 6; ++k) {
    int dl = (t >> 3) + k * 32;                  // 0..191
    int g = t & 7;                               // 8 lanes x 16B = 128B/row
    uint4 e8 = *(const uint4*)(etile + dl * 72 + g * 8);
    *(uint4*)(Ft + ((size_t)b * DIMD + dc * 192 + dl) * NTOK + ntile * 64 + g * 8) = e8;
  }
}

// standalone GEMM (final epilogue)
template <int TMD, int TND, int EPI>
__global__ __launch_bounds__(256) void mfma_bt(
    const unsigned short* __restrict__ A, const unsigned short* __restrict__ B,
    void* __restrict__ Cout, int K, int lda, int ldb, int ldc, int ntx,
    long long sA, long long sB, long long sC,
    const float* __restrict__ wg, const float* __restrict__ b1v,
    const float* __restrict__ b2v, const float* __restrict__ xres) {
  __shared__ __align__(16) unsigned short As[2 * 64 * TMD * 64];
  __shared__ __align__(16) unsigned short Bs[2 * 64 * TND * 64];
  gemm_body<TMD, TND, EPI>(As, Bs, blockIdx.x, A, B, Cout, K, lda, ldb, ldc, ntx,
                           sA, sB, sC, wg, b1v, b2v, xres);
}

// S-gemm, symmetric: only lower-triangle+diag 128^2 tiles (21 of 36 per
// batch-attn); off-diag tiles write the mirror too (EPI 2). 336 blocks.
__global__ __launch_bounds__(256) void sgemm_s(
    const unsigned short* __restrict__ Ft1, const float* __restrict__ civ1,
    const unsigned short* __restrict__ Ft2, const float* __restrict__ civ2,
    unsigned short* __restrict__ Ca, unsigned short* __restrict__ Cb) {
  __shared__ __align__(16) unsigned short As[2 * 128 * 64];
  __shared__ __align__(16) unsigned short Bs[2 * 128 * 64];
  int bid = blockIdx.x;                // 0..335
  int bz = bid & 7, r = bid >> 3;      // r 0..41
  bool second = r >= 21;
  int tri = second ? r - 21 : r;
  int by = 0;
  while ((by + 1) * (by + 2) / 2 <= tri) ++by;
  int bx = tri - by * (by + 1) / 2;    // bx <= by
  const unsigned short* F = second ? Ft2 : Ft1;
  const float* civ = second ? civ2 : civ1;
  unsigned short* C = second ? Cb : Ca;
  int enc = ((by * 6 + bx) << 3) | bz;
  gemm_body<2, 2, 2>(As, Bs, enc, F, F, C, NTOK, NTOK, NTOK, 1536, 6,
                     768LL * NTOK, 768LL * NTOK, 768LL * 1536,
                     nullptr, civ, nullptr, nullptr);
}

// s2 (Bt = Wcat . Scat^T, 288 blocks, 128x128) + pack_x (6144 BW-bound blocks;
// xb aliases the Ft region, dead only after sgemm_s -> must stay here)
__global__ __launch_bounds__(256) void s2_packx_kernel(
    const unsigned short* __restrict__ Wcat, const unsigned short* __restrict__ Scat,
    unsigned short* __restrict__ Bt, const float* __restrict__ x,
    unsigned short* __restrict__ xb) {
  __shared__ __align__(16) unsigned short As[2 * 128 * 64];
  __shared__ __align__(16) unsigned short Bs[2 * 128 * 64];
  int blk = blockIdx.x;
  if (blk < 288) {
    gemm_body<2, 2, 0>(As, Bs, blk, Wcat, Scat, Bt, 1536, 1536, 1536, 768, 6,
                       0LL, 768LL * 1536, 768LL * 768,
                       nullptr, nullptr, nullptr, nullptr);
  } else {
    packx_body(blk - 288, x, xb);
  }
}

// ---------------------------------------------------------------------------
// launch
// ---------------------------------------------------------------------------
extern "C" void kernel_launch(void* const* d_in, const int* in_sizes, int n_in,
                              void* d_out, int out_size, void* d_ws, size_t ws_size,
                              hipStream_t stream) {
  const float* x  = (const float*)d_in[0];
  const float* x2 = (const float*)d_in[1];
  const float* x3 = (const float*)d_in[2];
  const float* W1 = (const float*)d_in[3];
  const float* b1 = (const float*)d_in[4];
  const float* W2 = (const float*)d_in[5];
  const float* b2 = (const float*)d_in[6];
  const float* w  = (const float*)d_in[7];
  float* out = (float*)d_out;
  char* ws = (char*)d_ws;

  // workspace layout (bytes), total 74891264:
  // Ft1 0 (25165824) | Ft2 25165824 (25165824) | Scat 50331648 (18874368) |
  // Wcat 69206016 (2359296) | csp1 71565312 (1572864) | csp2 73138176 (1572864) |
  // rsf 74711040 (131072) | civ1 74842112 (24576) | civ2 74866688 (24576).
  // Bt aliases Ft1 (dead after sgemm_s); xb aliases Ft1+9437184.
  unsigned short* Ft1  = (unsigned short*)(ws + 0);
  unsigned short* Ft2  = (unsigned short*)(ws + 25165824);
  unsigned short* Scat = (unsigned short*)(ws + 50331648);
  unsigned short* Wcat = (unsigned short*)(ws + 69206016);
  float* csp1 = (float*)(ws + 71565312);
  float* csp2 = (float*)(ws + 73138176);
  float* rsf  = (float*)(ws + 74711040);
  float* civ1 = (float*)(ws + 74842112);
  float* civ2 = (float*)(ws + 74866688);
  unsigned short* Bt = (unsigned short*)(ws + 0);
  unsigned short* xb = (unsigned short*)(ws + 9437184);

  dim3 blk(256);

  // 1: rowsum + colsum partials of exp(x2),exp(x3) + pack_w
  rowcol_kernel<<<1600, blk, 0, stream>>>(x2, x3, csp1, csp2, rsf, W1, W2, Wcat, 576);
  // 2: Ft = (exp(x) * sqrt(rowsum_inv))^T + colsum finalize (1/sum)
  ft_kernel<<<2096, blk, 0, stream>>>(x2, x3, rsf, Ft1, Ft2, csp1, csp2, civ1, civ2);
  // 3: Scat = Ft.Ft^T * diag(colsum^-1), symmetric-triangle blocks
  sgemm_s<<<336, blk, 0, stream>>>(Ft1, civ1, Ft2, civ2, Scat, Scat + 768);
  // 4: Bt = Wcat . Scat^T (K=1536) + pack x->bf16
  s2_packx_kernel<<<6432, blk, 0, stream>>>(Wcat, Scat, Bt, x, xb);
  // 5: out = gate * xb.Bt^T + gate*(b1+b2) + x
  mfma_bt<2, 2, 1><<<768, blk, 0, stream>>>(xb, Bt, out, DIMD, DIMD, DIMD, DIMD, 6,
                                            (long long)NTOK * DIMD, 768LL * 768,
                                            (long long)NTOK * DIMD, w, b1, b2, x);
}